// Round 1
// baseline (2906.572 us; speedup 1.0000x reference)
//
#include <hip/hip_runtime.h>
#include <cstdint>
#include <cstddef>

// DGCNN forward, fp32 baseline.
// Structure:
//   per layer l: norms -> knn(top-20 via tiled Gram + per-thread top-k) ->
//                conv (h = W1*nbr + (W2-W1)*ctr + b; max over k kept, stats
//                Σh/Σh² accumulated over all k via atomics) -> bnrelu (BN+LeakyReLU
//                applied post-max; valid since g=1>0 makes the transform monotone)
//   final: GEMM tiles + max-over-n epilogue via monotonic-encoded atomicMax, bias after.
// Workspace: idx[8][2048][20] | xcat[8][2048][512] (channel slices 0/64/128/256) |
//            norms[8*2048] | stats[4][2][256] | outenc[8][1024]   (~35 MB)

constexpr int NB = 8;
constexpr int NP = 2048;
constexpr int KK = 20;

#define FMA16(AV, BV, ACC)                                          \
  {                                                                 \
    const float _a[4] = {AV.x, AV.y, AV.z, AV.w};                   \
    const float _b[4] = {BV.x, BV.y, BV.z, BV.w};                   \
    _Pragma("unroll")                                               \
    for (int _e = 0; _e < 4; ++_e) {                                \
      _Pragma("unroll")                                             \
      for (int _f = 0; _f < 4; ++_f)                                \
        ACC[_e][_f] = fmaf(_a[_e], _b[_f], ACC[_e][_f]);            \
    }                                                               \
  }

// ---------------- norms ----------------
template<int C, int RS>
__global__ __launch_bounds__(256) void norms_kernel(const float* __restrict__ X,
                                                    float* __restrict__ out) {
  const int g = blockIdx.x * 256 + threadIdx.x;  // 0 .. NB*NP-1
  const float* p = X + (size_t)g * RS;
  float s = 0.f;
#pragma unroll
  for (int c = 0; c < C; ++c) s = fmaf(p[c], p[c], s);
  out[g] = s;
}

// ---------------- knn ----------------
// Block: 64 query rows (i0..i0+63) of batch b; loops over all 2048 j in tiles of 64.
// Transposed LDS tiles [c][row], stride 64 (2-way bank aliasing: free on gfx950).
template<int C, int CHUNK, int NCH, int RS>
__global__ __launch_bounds__(256) void knn_kernel(const float* __restrict__ X,
                                                  const float* __restrict__ norms,
                                                  int* __restrict__ idxout) {
  constexpr int CC = NCH * CHUNK;
  constexpr int XJ = CC * 64;                               // xj chunk region
  constexpr int ND = (CHUNK == 64) ? XJ : XJ + CHUNK * 64;  // negd region (aliases xj when 64)
  constexpr int TAIL = ND + 64 * 64;
  constexpr int LISTS = 256 * KK * 2;                       // merge lists (aliased at end)
  constexpr int NIO = (TAIL > LISTS) ? TAIL : LISTS;
  constexpr int SBF = NIO + 128;
  __shared__ float sb[SBF];

  const int t = threadIdx.x;
  const int lane = t & 63;
  const int wid = t >> 6;
  const int tr = t & 15;   // row group (4 rows)
  const int tc = t >> 4;   // col group (4 cols)
  const int b = blockIdx.y;
  const int i0 = blockIdx.x * 64;

  // stage XiT [c][row] (full C) + ni
  if constexpr (CHUNK == 4) {
    const int c = t >> 6, row = t & 63;
    sb[c * 64 + row] = (c < C) ? X[(size_t)(b * NP + i0 + row) * RS + c] : 0.f;
  } else {
#pragma unroll
    for (int i = 0; i < CC / 16; ++i) {
      const int q = wid + i * 4;
      const float4 v = *reinterpret_cast<const float4*>(
          X + (size_t)(b * NP + i0 + lane) * RS + q * 4);
      sb[(q * 4 + 0) * 64 + lane] = v.x;
      sb[(q * 4 + 1) * 64 + lane] = v.y;
      sb[(q * 4 + 2) * 64 + lane] = v.z;
      sb[(q * 4 + 3) * 64 + lane] = v.w;
    }
  }
  if (t < 64) sb[NIO + t] = norms[b * NP + i0 + t];

  // per-thread top-20 (unrolled-register min-replace list)
  float lv[KK]; int li[KK];
#pragma unroll
  for (int e = 0; e < KK; ++e) { lv[e] = -__builtin_inff(); li[e] = 0; }
  float minv = -__builtin_inff(); int minpos = 0;

  auto ins = [&](float nv, int nj) {
    if (nv > minv) {  // strict > keeps earlier (lower-j) on ties, matching stable top-k
#pragma unroll
      for (int e = 0; e < KK; ++e)
        if (e == minpos) { lv[e] = nv; li[e] = nj; }
      minv = lv[0]; minpos = 0;
#pragma unroll
      for (int e = 1; e < KK; ++e)
        if (lv[e] < minv) { minv = lv[e]; minpos = e; }
    }
  };

  const int rsel = t >> 2, qsel = t & 3;  // selection: 4 threads per row, 16 cols each

  for (int s = 0; s < NP / 64; ++s) {
    const int j0 = s * 64;
    float acc[4][4];
#pragma unroll
    for (int e = 0; e < 4; ++e) {
#pragma unroll
      for (int f = 0; f < 4; ++f) acc[e][f] = 0.f;
    }

#pragma unroll
    for (int cc = 0; cc < NCH; ++cc) {
      __syncthreads();
      if constexpr (CHUNK == 4) {
        const int c = t >> 6, row = t & 63;
        sb[XJ + c * 64 + row] = (c < C) ? X[(size_t)(b * NP + j0 + row) * RS + c] : 0.f;
      } else {
#pragma unroll
        for (int i = 0; i < CHUNK / 16; ++i) {
          const int q = wid + i * 4;
          const float4 v = *reinterpret_cast<const float4*>(
              X + (size_t)(b * NP + j0 + lane) * RS + cc * CHUNK + q * 4);
          sb[XJ + (q * 4 + 0) * 64 + lane] = v.x;
          sb[XJ + (q * 4 + 1) * 64 + lane] = v.y;
          sb[XJ + (q * 4 + 2) * 64 + lane] = v.z;
          sb[XJ + (q * 4 + 3) * 64 + lane] = v.w;
        }
      }
      if (cc == 0 && t < 64) sb[NIO + 64 + t] = norms[b * NP + j0 + t];
      __syncthreads();
#pragma unroll
      for (int c = 0; c < CHUNK; ++c) {
        const float4 a = *reinterpret_cast<const float4*>(sb + (cc * CHUNK + c) * 64 + tr * 4);
        const float4 bb = *reinterpret_cast<const float4*>(sb + XJ + c * 64 + tc * 4);
        FMA16(a, bb, acc);
      }
    }
    __syncthreads();
    // negd = 2*dot - |xi|^2 - |xj|^2  (max == nearest; diag ~ 0 keeps self in top-20)
#pragma unroll
    for (int e = 0; e < 4; ++e) {
      const int row = tr * 4 + e;
      const float ni = sb[NIO + row];
      float4 nd;
      nd.x = 2.f * acc[e][0] - ni - sb[NIO + 64 + tc * 4 + 0];
      nd.y = 2.f * acc[e][1] - ni - sb[NIO + 64 + tc * 4 + 1];
      nd.z = 2.f * acc[e][2] - ni - sb[NIO + 64 + tc * 4 + 2];
      nd.w = 2.f * acc[e][3] - ni - sb[NIO + 64 + tc * 4 + 3];
      *reinterpret_cast<float4*>(sb + ND + row * 64 + tc * 4) = nd;
    }
    __syncthreads();
    {
      const float* rowp = sb + ND + rsel * 64 + qsel * 16;
#pragma unroll
      for (int m = 0; m < 4; ++m) {
        const float4 dv = *reinterpret_cast<const float4*>(rowp + m * 4);
        const int jb = j0 + qsel * 16 + m * 4;
        ins(dv.x, jb + 0);
        ins(dv.y, jb + 1);
        ins(dv.z, jb + 2);
        ins(dv.w, jb + 3);
      }
    }
  }

  // merge the 4 per-row lists
  __syncthreads();
  {
    float* Lv = sb;
    int* Li = reinterpret_cast<int*>(sb + 256 * KK);
#pragma unroll
    for (int e = 0; e < KK; ++e) { Lv[t * KK + e] = lv[e]; Li[t * KK + e] = li[e]; }
  }
  __syncthreads();
  if ((t & 3) == 0) {
    const float* Lv = sb;
    const int* Li = reinterpret_cast<const int*>(sb + 256 * KK);
    for (int sq = 1; sq < 4; ++sq)
      for (int e = 0; e < KK; ++e)
        ins(Lv[(t + sq) * KK + e], Li[(t + sq) * KK + e]);
    int* op = idxout + (size_t)(b * NP + i0 + rsel) * KK;
#pragma unroll
    for (int e = 0; e < KK; ++e) op[e] = li[e];
  }
}

// ---------------- edge conv ----------------
// Block: 64 n-rows x 64 o-cols of batch b. Phase0: T = (W2-W1)*ctr + b (per-thread regs).
// Then 20 k-steps of gathered [64 x C] x W1^T [C x 64], epilogue max/sum/sumsq.
template<int C, int CHUNK, int NCH, int O, int RSIN>
__global__ __launch_bounds__(256) void conv_kernel(const float* __restrict__ X,
    const int* __restrict__ nbr, const float* __restrict__ W,
    const float* __restrict__ bias, float* __restrict__ outf,
    float* __restrict__ ssum, float* __restrict__ ssq) {
  constexpr int CC = NCH * CHUNK;
  constexpr int WREG = (CC * 64 > 2048) ? CC * 64 : 2048;  // W1T region (stats alias at end)
  constexpr int AB = WREG;                                 // A-chunk region
  constexpr int SBF = WREG + CHUNK * 64;
  __shared__ float sb[SBF];
  constexpr int WS = 2 * C;

  const int t = threadIdx.x, lane = t & 63, wid = t >> 6, tr = t & 15, tc = t >> 4;
  const int b = blockIdx.z, n0 = blockIdx.x * 64, o0 = blockIdx.y * 64;

  float T[4][4];
  {
    float acc[4][4] = {};
#pragma unroll
    for (int cc = 0; cc < NCH; ++cc) {
      __syncthreads();
      if constexpr (CHUNK == 4) {
        const int c = t >> 6, row = t & 63;
        sb[AB + c * 64 + row] = (c < C) ? X[(size_t)(b * NP + n0 + row) * RSIN + c] : 0.f;
        sb[c * 64 + row] = (c < C) ? (W[(o0 + row) * WS + C + c] - W[(o0 + row) * WS + c]) : 0.f;
      } else {
#pragma unroll
        for (int i = 0; i < CHUNK / 16; ++i) {
          const int q = wid + i * 4;
          const float4 v = *reinterpret_cast<const float4*>(
              X + (size_t)(b * NP + n0 + lane) * RSIN + cc * CHUNK + q * 4);
          sb[AB + (q * 4 + 0) * 64 + lane] = v.x;
          sb[AB + (q * 4 + 1) * 64 + lane] = v.y;
          sb[AB + (q * 4 + 2) * 64 + lane] = v.z;
          sb[AB + (q * 4 + 3) * 64 + lane] = v.w;
          const float4 w1 = *reinterpret_cast<const float4*>(
              W + (size_t)(o0 + lane) * WS + cc * CHUNK + q * 4);
          const float4 w2 = *reinterpret_cast<const float4*>(
              W + (size_t)(o0 + lane) * WS + C + cc * CHUNK + q * 4);
          sb[(q * 4 + 0) * 64 + lane] = w2.x - w1.x;
          sb[(q * 4 + 1) * 64 + lane] = w2.y - w1.y;
          sb[(q * 4 + 2) * 64 + lane] = w2.z - w1.z;
          sb[(q * 4 + 3) * 64 + lane] = w2.w - w1.w;
        }
      }
      __syncthreads();
#pragma unroll
      for (int c = 0; c < CHUNK; ++c) {  // chunk-local reads for both operands in phase 0
        const float4 a = *reinterpret_cast<const float4*>(sb + AB + c * 64 + tr * 4);
        const float4 bb = *reinterpret_cast<const float4*>(sb + c * 64 + tc * 4);
        FMA16(a, bb, acc);
      }
    }
    const float4 bv = *reinterpret_cast<const float4*>(bias + o0 + tc * 4);
    const float bva[4] = {bv.x, bv.y, bv.z, bv.w};
#pragma unroll
    for (int e = 0; e < 4; ++e) {
#pragma unroll
      for (int f = 0; f < 4; ++f) T[e][f] = acc[e][f] + bva[f];
    }
  }

  // stage full W1T
  __syncthreads();
  if constexpr (CHUNK == 4) {
    const int c = t >> 6, row = t & 63;
    sb[c * 64 + row] = (c < C) ? W[(o0 + row) * WS + c] : 0.f;
  } else {
#pragma unroll
    for (int i = 0; i < CC / 16; ++i) {
      const int q = wid + i * 4;
      const float4 w1 = *reinterpret_cast<const float4*>(
          W + (size_t)(o0 + lane) * WS + q * 4);
      sb[(q * 4 + 0) * 64 + lane] = w1.x;
      sb[(q * 4 + 1) * 64 + lane] = w1.y;
      sb[(q * 4 + 2) * 64 + lane] = w1.z;
      sb[(q * 4 + 3) * 64 + lane] = w1.w;
    }
  }

  float mx[4][4], sm[4][4], s2[4][4];
#pragma unroll
  for (int e = 0; e < 4; ++e) {
#pragma unroll
    for (int f = 0; f < 4; ++f) { mx[e][f] = -__builtin_inff(); sm[e][f] = 0.f; s2[e][f] = 0.f; }
  }

  for (int k = 0; k < KK; ++k) {
    const int jr = nbr[(size_t)(b * NP + n0 + lane) * KK + k];
    float acc[4][4] = {};
#pragma unroll
    for (int cc = 0; cc < NCH; ++cc) {
      __syncthreads();
      if constexpr (CHUNK == 4) {
        const int c = t >> 6, row = t & 63;
        const int jrr = nbr[(size_t)(b * NP + n0 + row) * KK + k];
        sb[AB + c * 64 + row] = (c < C) ? X[(size_t)(b * NP + jrr) * RSIN + c] : 0.f;
      } else {
#pragma unroll
        for (int i = 0; i < CHUNK / 16; ++i) {
          const int q = wid + i * 4;
          const float4 v = *reinterpret_cast<const float4*>(
              X + (size_t)(b * NP + jr) * RSIN + cc * CHUNK + q * 4);
          sb[AB + (q * 4 + 0) * 64 + lane] = v.x;
          sb[AB + (q * 4 + 1) * 64 + lane] = v.y;
          sb[AB + (q * 4 + 2) * 64 + lane] = v.z;
          sb[AB + (q * 4 + 3) * 64 + lane] = v.w;
        }
      }
      __syncthreads();
#pragma unroll
      for (int c = 0; c < CHUNK; ++c) {
        const float4 a = *reinterpret_cast<const float4*>(sb + AB + c * 64 + tr * 4);
        const float4 bb = *reinterpret_cast<const float4*>(sb + (cc * CHUNK + c) * 64 + tc * 4);
        FMA16(a, bb, acc);
      }
    }
#pragma unroll
    for (int e = 0; e < 4; ++e) {
#pragma unroll
      for (int f = 0; f < 4; ++f) {
        const float h = acc[e][f] + T[e][f];
        mx[e][f] = fmaxf(mx[e][f], h);
        sm[e][f] += h;
        s2[e][f] = fmaf(h, h, s2[e][f]);
      }
    }
  }

  // write max-over-k (pre-BN) to xcat slice
#pragma unroll
  for (int e = 0; e < 4; ++e) {
    float4 o4;
    o4.x = mx[e][0]; o4.y = mx[e][1]; o4.z = mx[e][2]; o4.w = mx[e][3];
    *reinterpret_cast<float4*>(outf + (size_t)(b * NP + n0 + tr * 4 + e) * 512 + o0 + tc * 4) = o4;
  }

  // per-channel stats reduce (alias over W1T region; dead after k-loop)
  __syncthreads();
#pragma unroll
  for (int f = 0; f < 4; ++f) {
    sb[tr * 64 + tc * 4 + f] = sm[0][f] + sm[1][f] + sm[2][f] + sm[3][f];
    sb[1024 + tr * 64 + tc * 4 + f] = s2[0][f] + s2[1][f] + s2[2][f] + s2[3][f];
  }
  __syncthreads();
  if (t < 64) {
    float S = 0.f, Q = 0.f;
#pragma unroll
    for (int r = 0; r < 16; ++r) { S += sb[r * 64 + t]; Q += sb[1024 + r * 64 + t]; }
    atomicAdd(ssum + o0 + t, S);
    atomicAdd(ssq + o0 + t, Q);
  }
}

// ---------------- bn + leaky relu (in place, post-max) ----------------
template<int O>
__global__ __launch_bounds__(256) void bnrelu_kernel(float* __restrict__ feat,
    const float* __restrict__ ssum, const float* __restrict__ ssq,
    const float* __restrict__ g, const float* __restrict__ be) {
  constexpr float INV = 1.0f / 327680.0f;  // B*N*K
  const int t4 = blockIdx.x * 256 + threadIdx.x;
  const int e0 = t4 * 4;
  const int r = e0 / O, c = e0 % O;
  float4 h = *reinterpret_cast<float4*>(feat + (size_t)r * 512 + c);
  float hv[4] = {h.x, h.y, h.z, h.w};
#pragma unroll
  for (int j = 0; j < 4; ++j) {
    const int col = c + j;
    const float m = ssum[col] * INV;
    const float v = ssq[col] * INV - m * m;
    const float sc = g[col] / sqrtf(v + 1e-5f);
    const float val = (hv[j] - m) * sc + be[col];
    hv[j] = (val >= 0.f) ? val : 0.2f * val;
  }
  h.x = hv[0]; h.y = hv[1]; h.z = hv[2]; h.w = hv[3];
  *reinterpret_cast<float4*>(feat + (size_t)r * 512 + c) = h;
}

// ---------------- final conv + global max pool ----------------
__global__ __launch_bounds__(256) void final_kernel(const float* __restrict__ xcat,
    const float* __restrict__ Wf, unsigned int* __restrict__ outenc) {
  __shared__ float sb[9216];  // AT 4096 | WfT 4096 | mred 1024
  const int t = threadIdx.x, lane = t & 63, wid = t >> 6, tr = t & 15, tc = t >> 4;
  const int b = blockIdx.z, n0 = blockIdx.x * 64, o0 = blockIdx.y * 64;
  float acc[4][4] = {};
  for (int cc = 0; cc < 8; ++cc) {
    __syncthreads();
#pragma unroll
    for (int i = 0; i < 4; ++i) {
      const int q = wid + i * 4;
      const float4 v = *reinterpret_cast<const float4*>(
          xcat + (size_t)(b * NP + n0 + lane) * 512 + cc * 64 + q * 4);
      sb[(q * 4 + 0) * 64 + lane] = v.x;
      sb[(q * 4 + 1) * 64 + lane] = v.y;
      sb[(q * 4 + 2) * 64 + lane] = v.z;
      sb[(q * 4 + 3) * 64 + lane] = v.w;
      const float4 w4 = *reinterpret_cast<const float4*>(
          Wf + (size_t)(o0 + lane) * 512 + cc * 64 + q * 4);
      sb[4096 + (q * 4 + 0) * 64 + lane] = w4.x;
      sb[4096 + (q * 4 + 1) * 64 + lane] = w4.y;
      sb[4096 + (q * 4 + 2) * 64 + lane] = w4.z;
      sb[4096 + (q * 4 + 3) * 64 + lane] = w4.w;
    }
    __syncthreads();
#pragma unroll
    for (int c = 0; c < 64; ++c) {
      const float4 a = *reinterpret_cast<const float4*>(sb + c * 64 + tr * 4);
      const float4 bb = *reinterpret_cast<const float4*>(sb + 4096 + c * 64 + tc * 4);
      FMA16(a, bb, acc);
    }
  }
  float m4[4];
#pragma unroll
  for (int f = 0; f < 4; ++f)
    m4[f] = fmaxf(fmaxf(acc[0][f], acc[1][f]), fmaxf(acc[2][f], acc[3][f]));
  __syncthreads();
#pragma unroll
  for (int f = 0; f < 4; ++f) sb[8192 + tr * 64 + tc * 4 + f] = m4[f];
  __syncthreads();
  if (t < 64) {
    float M = -__builtin_inff();
#pragma unroll
    for (int r = 0; r < 16; ++r) M = fmaxf(M, sb[8192 + r * 64 + t]);
    const unsigned ubits = __float_as_uint(M);
    const unsigned key = (ubits & 0x80000000u) ? ~ubits : (ubits | 0x80000000u);
    atomicMax(outenc + b * 1024 + o0 + t, key);
  }
}

__global__ __launch_bounds__(256) void decode_kernel(const unsigned int* __restrict__ enc,
    const float* __restrict__ bf, float* __restrict__ out) {
  const int gid = blockIdx.x * 256 + threadIdx.x;  // 8192
  const unsigned key = enc[gid];
  const unsigned ubits = (key & 0x80000000u) ? (key & 0x7fffffffu) : ~key;
  out[gid] = __uint_as_float(ubits) + bf[gid & 1023];
}

// ---------------- launch ----------------
extern "C" void kernel_launch(void* const* d_in, const int* in_sizes, int n_in,
                              void* d_out, int out_size, void* d_ws, size_t ws_size,
                              hipStream_t stream) {
  (void)in_sizes; (void)n_in; (void)out_size; (void)ws_size;
  const float* x   = (const float*)d_in[0];
  const float* W0  = (const float*)d_in[1];
  const float* b0  = (const float*)d_in[2];
  const float* g0  = (const float*)d_in[3];
  const float* be0 = (const float*)d_in[4];
  const float* W1  = (const float*)d_in[5];
  const float* b1  = (const float*)d_in[6];
  const float* g1  = (const float*)d_in[7];
  const float* be1 = (const float*)d_in[8];
  const float* W2  = (const float*)d_in[9];
  const float* b2  = (const float*)d_in[10];
  const float* g2  = (const float*)d_in[11];
  const float* be2 = (const float*)d_in[12];
  const float* W3  = (const float*)d_in[13];
  const float* b3  = (const float*)d_in[14];
  const float* g3  = (const float*)d_in[15];
  const float* be3 = (const float*)d_in[16];
  const float* Wf  = (const float*)d_in[17];
  const float* bf  = (const float*)d_in[18];

  float* wsf = (float*)d_ws;
  int* idxb = (int*)d_ws;                                  // 327,680 ints
  float* xcat = wsf + 327680;                              // [8][2048][512]
  float* norms = xcat + (size_t)NB * NP * 512;             // [8*2048]
  float* stats = norms + NB * NP;                          // [4][2][256]
  unsigned int* outenc = (unsigned int*)(stats + 2048);    // [8][1024]

  hipMemsetAsync(stats, 0, 2048 * sizeof(float), stream);
  hipMemsetAsync(outenc, 0, NB * 1024 * sizeof(unsigned int), stream);

  const dim3 blk(256, 1, 1);

  // Layer 0 (C=3 -> 64, xcat cols [0,64))
  norms_kernel<3, 3><<<dim3(64), blk, 0, stream>>>(x, norms);
  knn_kernel<3, 4, 1, 3><<<dim3(32, 8), blk, 0, stream>>>(x, norms, idxb);
  conv_kernel<3, 4, 1, 64, 3><<<dim3(32, 1, 8), blk, 0, stream>>>(
      x, idxb, W0, b0, xcat, stats, stats + 256);
  bnrelu_kernel<64><<<dim3(1024), blk, 0, stream>>>(xcat, stats, stats + 256, g0, be0);

  // Layer 1 (64 -> 64, cols [64,128))
  norms_kernel<64, 512><<<dim3(64), blk, 0, stream>>>(xcat, norms);
  knn_kernel<64, 64, 1, 512><<<dim3(32, 8), blk, 0, stream>>>(xcat, norms, idxb);
  conv_kernel<64, 64, 1, 64, 512><<<dim3(32, 1, 8), blk, 0, stream>>>(
      xcat, idxb, W1, b1, xcat + 64, stats + 512, stats + 768);
  bnrelu_kernel<64><<<dim3(1024), blk, 0, stream>>>(xcat + 64, stats + 512, stats + 768, g1, be1);

  // Layer 2 (64 -> 128, cols [128,256))
  norms_kernel<64, 512><<<dim3(64), blk, 0, stream>>>(xcat + 64, norms);
  knn_kernel<64, 64, 1, 512><<<dim3(32, 8), blk, 0, stream>>>(xcat + 64, norms, idxb);
  conv_kernel<64, 64, 1, 128, 512><<<dim3(32, 2, 8), blk, 0, stream>>>(
      xcat + 64, idxb, W2, b2, xcat + 128, stats + 1024, stats + 1280);
  bnrelu_kernel<128><<<dim3(2048), blk, 0, stream>>>(xcat + 128, stats + 1024, stats + 1280, g2, be2);

  // Layer 3 (128 -> 256, cols [256,512))
  norms_kernel<128, 512><<<dim3(64), blk, 0, stream>>>(xcat + 128, norms);
  knn_kernel<128, 64, 2, 512><<<dim3(32, 8), blk, 0, stream>>>(xcat + 128, norms, idxb);
  conv_kernel<128, 64, 2, 256, 512><<<dim3(32, 4, 8), blk, 0, stream>>>(
      xcat + 128, idxb, W3, b3, xcat + 256, stats + 1536, stats + 1792);
  bnrelu_kernel<256><<<dim3(4096), blk, 0, stream>>>(xcat + 256, stats + 1536, stats + 1792, g3, be3);

  // Final 1x1 conv + global max pool
  final_kernel<<<dim3(32, 16, 8), blk, 0, stream>>>(xcat, Wf, outenc);
  decode_kernel<<<dim3(32), blk, 0, stream>>>(outenc, bf, (float*)d_out);
}

// Round 2
// 2294.916 us; speedup vs baseline: 1.2665x; 1.2665x over previous
//
#include <hip/hip_runtime.h>
#include <cstdint>
#include <cstddef>

// DGCNN forward, fp32. R2: knn j-split x4 (4 blocks/CU vs 1), shfl-based in-wave
// top-20 merge (drops 40KB LDS lists region), global candidate buffer + merge kernel.
// Layer 0 unified onto padded C=4 path.

constexpr int NB = 8;
constexpr int NP = 2048;
constexpr int KK = 20;
constexpr int JT = 4;  // knn j-split factor

#define FMA16(AV, BV, ACC)                                          \
  {                                                                 \
    const float _a[4] = {AV.x, AV.y, AV.z, AV.w};                   \
    const float _b[4] = {BV.x, BV.y, BV.z, BV.w};                   \
    _Pragma("unroll")                                               \
    for (int _e = 0; _e < 4; ++_e) {                                \
      _Pragma("unroll")                                             \
      for (int _f = 0; _f < 4; ++_f)                                \
        ACC[_e][_f] = fmaf(_a[_e], _b[_f], ACC[_e][_f]);            \
    }                                                               \
  }

// ---------------- pad x -> x4 ----------------
__global__ __launch_bounds__(256) void pad_kernel(const float* __restrict__ x,
                                                  float* __restrict__ x4) {
  const int p = blockIdx.x * 256 + threadIdx.x;  // 16384 points
  float4 v;
  v.x = x[p * 3 + 0]; v.y = x[p * 3 + 1]; v.z = x[p * 3 + 2]; v.w = 0.f;
  *reinterpret_cast<float4*>(x4 + (size_t)p * 4) = v;
}

// ---------------- norms ----------------
template<int C, int RS>
__global__ __launch_bounds__(256) void norms_kernel(const float* __restrict__ X,
                                                    float* __restrict__ out) {
  const int g = blockIdx.x * 256 + threadIdx.x;  // 0 .. NB*NP-1
  const float* p = X + (size_t)g * RS;
  float s = 0.f;
#pragma unroll
  for (int c = 0; c < C; ++c) s = fmaf(p[c], p[c], s);
  out[g] = s;
}

// ---------------- knn (j-split) ----------------
// Block: 64 query rows of batch b, j in [js*512, js*512+512). Emits per-row
// top-20 candidates (val+idx) for this j-range. Transposed LDS tiles, stride 64.
template<int C, int CHUNK, int NCH, int RS>
__global__ __launch_bounds__(256) void knn_kernel(const float* __restrict__ X,
                                                  const float* __restrict__ norms,
                                                  float* __restrict__ cval,
                                                  int* __restrict__ cidx) {
  constexpr int CC = NCH * CHUNK;
  constexpr int XJ = CC * 64;                               // xj chunk region
  constexpr int ND = (CHUNK == 64) ? XJ : XJ + CHUNK * 64;  // negd (aliases xj when 64)
  constexpr int NIO = ND + 64 * 64;
  __shared__ float sb[NIO + 128];

  const int t = threadIdx.x;
  const int lane = t & 63;
  const int wid = t >> 6;
  const int tr = t & 15;   // row group (4 rows)
  const int tc = t >> 4;   // col group (4 cols)
  const int b = blockIdx.z;
  const int js = blockIdx.y;
  const int i0 = blockIdx.x * 64;

  // stage XiT [c][row] (full C) + ni
  if constexpr (CHUNK == 4) {
    const int c = t >> 6, row = t & 63;
    sb[c * 64 + row] = X[(size_t)(b * NP + i0 + row) * RS + c];
  } else {
#pragma unroll
    for (int i = 0; i < CC / 16; ++i) {
      const int q = wid + i * 4;
      const float4 v = *reinterpret_cast<const float4*>(
          X + (size_t)(b * NP + i0 + lane) * RS + q * 4);
      sb[(q * 4 + 0) * 64 + lane] = v.x;
      sb[(q * 4 + 1) * 64 + lane] = v.y;
      sb[(q * 4 + 2) * 64 + lane] = v.z;
      sb[(q * 4 + 3) * 64 + lane] = v.w;
    }
  }
  if (t < 64) sb[NIO + t] = norms[b * NP + i0 + t];

  // per-thread top-20 (unrolled-register min-replace list)
  float lv[KK]; int li[KK];
#pragma unroll
  for (int e = 0; e < KK; ++e) { lv[e] = -__builtin_inff(); li[e] = 0; }
  float minv = -__builtin_inff(); int minpos = 0;

  auto ins = [&](float nv, int nj) {
    if (nv > minv) {  // strict > keeps earlier (lower-j) on ties (stable top-k)
#pragma unroll
      for (int e = 0; e < KK; ++e)
        if (e == minpos) { lv[e] = nv; li[e] = nj; }
      minv = lv[0]; minpos = 0;
#pragma unroll
      for (int e = 1; e < KK; ++e)
        if (lv[e] < minv) { minv = lv[e]; minpos = e; }
    }
  };

  const int rsel = t >> 2, qsel = t & 3;  // selection: 4 threads/row, 16 cols each

  constexpr int STEPS = NP / 64 / JT;  // 8
  for (int s = js * STEPS; s < js * STEPS + STEPS; ++s) {
    const int j0 = s * 64;
    float acc[4][4];
#pragma unroll
    for (int e = 0; e < 4; ++e) {
#pragma unroll
      for (int f = 0; f < 4; ++f) acc[e][f] = 0.f;
    }

#pragma unroll
    for (int cc = 0; cc < NCH; ++cc) {
      __syncthreads();
      if constexpr (CHUNK == 4) {
        const int c = t >> 6, row = t & 63;
        sb[XJ + c * 64 + row] = X[(size_t)(b * NP + j0 + row) * RS + c];
      } else {
#pragma unroll
        for (int i = 0; i < CHUNK / 16; ++i) {
          const int q = wid + i * 4;
          const float4 v = *reinterpret_cast<const float4*>(
              X + (size_t)(b * NP + j0 + lane) * RS + cc * CHUNK + q * 4);
          sb[XJ + (q * 4 + 0) * 64 + lane] = v.x;
          sb[XJ + (q * 4 + 1) * 64 + lane] = v.y;
          sb[XJ + (q * 4 + 2) * 64 + lane] = v.z;
          sb[XJ + (q * 4 + 3) * 64 + lane] = v.w;
        }
      }
      if (cc == 0 && t < 64) sb[NIO + 64 + t] = norms[b * NP + j0 + t];
      __syncthreads();
#pragma unroll
      for (int c = 0; c < CHUNK; ++c) {
        const float4 a = *reinterpret_cast<const float4*>(sb + (cc * CHUNK + c) * 64 + tr * 4);
        const float4 bb = *reinterpret_cast<const float4*>(sb + XJ + c * 64 + tc * 4);
        FMA16(a, bb, acc);
      }
    }
    __syncthreads();
    // negd = 2*dot - |xi|^2 - |xj|^2
#pragma unroll
    for (int e = 0; e < 4; ++e) {
      const int row = tr * 4 + e;
      const float ni = sb[NIO + row];
      float4 nd;
      nd.x = 2.f * acc[e][0] - ni - sb[NIO + 64 + tc * 4 + 0];
      nd.y = 2.f * acc[e][1] - ni - sb[NIO + 64 + tc * 4 + 1];
      nd.z = 2.f * acc[e][2] - ni - sb[NIO + 64 + tc * 4 + 2];
      nd.w = 2.f * acc[e][3] - ni - sb[NIO + 64 + tc * 4 + 3];
      *reinterpret_cast<float4*>(sb + ND + row * 64 + tc * 4) = nd;
    }
    __syncthreads();
    {
      const float* rowp = sb + ND + rsel * 64 + qsel * 16;
#pragma unroll
      for (int m = 0; m < 4; ++m) {
        const float4 dv = *reinterpret_cast<const float4*>(rowp + m * 4);
        const int jb = j0 + qsel * 16 + m * 4;
        ins(dv.x, jb + 0);
        ins(dv.y, jb + 1);
        ins(dv.z, jb + 2);
        ins(dv.w, jb + 3);
      }
    }
  }

  // merge the 4 per-row selector lists in-wave via shfl (lanes base..base+3)
  const int base = lane & ~3;
  for (int sq = 1; sq < 4; ++sq) {
#pragma unroll
    for (int e = 0; e < KK; ++e) {
      const float v = __shfl(lv[e], base + sq);
      const int j = __shfl(li[e], base + sq);
      if (qsel == 0) ins(v, j);
    }
  }
  if (qsel == 0) {
    float* vp = cval + ((size_t)(b * NP + i0 + rsel) * JT + js) * KK;
    int* ip = cidx + ((size_t)(b * NP + i0 + rsel) * JT + js) * KK;
#pragma unroll
    for (int e = 0; e < KK; ++e) { vp[e] = lv[e]; ip[e] = li[e]; }
  }
}

// ---------------- knn candidate merge: 80 -> 20 per row ----------------
__global__ __launch_bounds__(256) void knn_merge_kernel(const float* __restrict__ cval,
    const int* __restrict__ cidx, int* __restrict__ idxout) {
  const int r = blockIdx.x * 256 + threadIdx.x;  // 16384 rows
  const float* vp = cval + (size_t)r * (JT * KK);
  const int* ip = cidx + (size_t)r * (JT * KK);
  float lv[KK]; int li[KK];
#pragma unroll
  for (int e = 0; e < KK; ++e) { lv[e] = vp[e]; li[e] = ip[e]; }
  float minv = lv[0]; int minpos = 0;
#pragma unroll
  for (int e = 1; e < KK; ++e)
    if (lv[e] < minv) { minv = lv[e]; minpos = e; }

  auto ins = [&](float nv, int nj) {
    if (nv > minv) {
#pragma unroll
      for (int e = 0; e < KK; ++e)
        if (e == minpos) { lv[e] = nv; li[e] = nj; }
      minv = lv[0]; minpos = 0;
#pragma unroll
      for (int e = 1; e < KK; ++e)
        if (lv[e] < minv) { minv = lv[e]; minpos = e; }
    }
  };

  for (int q = KK; q < JT * KK; ++q) ins(vp[q], ip[q]);
  int* op = idxout + (size_t)r * KK;
#pragma unroll
  for (int e = 0; e < KK; ++e) op[e] = li[e];
}

// ---------------- edge conv ----------------
template<int C, int CHUNK, int NCH, int O, int RSIN>
__global__ __launch_bounds__(256) void conv_kernel(const float* __restrict__ X,
    const int* __restrict__ nbr, const float* __restrict__ W,
    const float* __restrict__ bias, float* __restrict__ outf,
    float* __restrict__ ssum, float* __restrict__ ssq) {
  constexpr int CC = NCH * CHUNK;
  constexpr int WREG = (CC * 64 > 2048) ? CC * 64 : 2048;  // W1T region (stats alias)
  constexpr int AB = WREG;                                 // A-chunk region
  constexpr int SBF = WREG + CHUNK * 64;
  __shared__ float sb[SBF];
  constexpr int WS = 2 * C;

  const int t = threadIdx.x, lane = t & 63, wid = t >> 6, tr = t & 15, tc = t >> 4;
  const int b = blockIdx.z, n0 = blockIdx.x * 64, o0 = blockIdx.y * 64;

  float T[4][4];
  {
    float acc[4][4] = {};
#pragma unroll
    for (int cc = 0; cc < NCH; ++cc) {
      __syncthreads();
      if constexpr (CHUNK == 4) {
        const int c = t >> 6, row = t & 63;
        sb[AB + c * 64 + row] = (c < C) ? X[(size_t)(b * NP + n0 + row) * RSIN + c] : 0.f;
        sb[c * 64 + row] = (c < C) ? (W[(o0 + row) * WS + C + c] - W[(o0 + row) * WS + c]) : 0.f;
      } else {
#pragma unroll
        for (int i = 0; i < CHUNK / 16; ++i) {
          const int q = wid + i * 4;
          const float4 v = *reinterpret_cast<const float4*>(
              X + (size_t)(b * NP + n0 + lane) * RSIN + cc * CHUNK + q * 4);
          sb[AB + (q * 4 + 0) * 64 + lane] = v.x;
          sb[AB + (q * 4 + 1) * 64 + lane] = v.y;
          sb[AB + (q * 4 + 2) * 64 + lane] = v.z;
          sb[AB + (q * 4 + 3) * 64 + lane] = v.w;
          const float4 w1 = *reinterpret_cast<const float4*>(
              W + (size_t)(o0 + lane) * WS + cc * CHUNK + q * 4);
          const float4 w2 = *reinterpret_cast<const float4*>(
              W + (size_t)(o0 + lane) * WS + C + cc * CHUNK + q * 4);
          sb[(q * 4 + 0) * 64 + lane] = w2.x - w1.x;
          sb[(q * 4 + 1) * 64 + lane] = w2.y - w1.y;
          sb[(q * 4 + 2) * 64 + lane] = w2.z - w1.z;
          sb[(q * 4 + 3) * 64 + lane] = w2.w - w1.w;
        }
      }
      __syncthreads();
#pragma unroll
      for (int c = 0; c < CHUNK; ++c) {
        const float4 a = *reinterpret_cast<const float4*>(sb + AB + c * 64 + tr * 4);
        const float4 bb = *reinterpret_cast<const float4*>(sb + c * 64 + tc * 4);
        FMA16(a, bb, acc);
      }
    }
    const float4 bv = *reinterpret_cast<const float4*>(bias + o0 + tc * 4);
    const float bva[4] = {bv.x, bv.y, bv.z, bv.w};
#pragma unroll
    for (int e = 0; e < 4; ++e) {
#pragma unroll
      for (int f = 0; f < 4; ++f) T[e][f] = acc[e][f] + bva[f];
    }
  }

  // stage full W1T
  __syncthreads();
  if constexpr (CHUNK == 4) {
    const int c = t >> 6, row = t & 63;
    sb[c * 64 + row] = (c < C) ? W[(o0 + row) * WS + c] : 0.f;
  } else {
#pragma unroll
    for (int i = 0; i < CC / 16; ++i) {
      const int q = wid + i * 4;
      const float4 w1 = *reinterpret_cast<const float4*>(
          W + (size_t)(o0 + lane) * WS + q * 4);
      sb[(q * 4 + 0) * 64 + lane] = w1.x;
      sb[(q * 4 + 1) * 64 + lane] = w1.y;
      sb[(q * 4 + 2) * 64 + lane] = w1.z;
      sb[(q * 4 + 3) * 64 + lane] = w1.w;
    }
  }

  float mx[4][4], sm[4][4], s2[4][4];
#pragma unroll
  for (int e = 0; e < 4; ++e) {
#pragma unroll
    for (int f = 0; f < 4; ++f) { mx[e][f] = -__builtin_inff(); sm[e][f] = 0.f; s2[e][f] = 0.f; }
  }

  for (int k = 0; k < KK; ++k) {
    const int jr = nbr[(size_t)(b * NP + n0 + lane) * KK + k];
    float acc[4][4] = {};
#pragma unroll
    for (int cc = 0; cc < NCH; ++cc) {
      __syncthreads();
      if constexpr (CHUNK == 4) {
        const int c = t >> 6, row = t & 63;
        const int jrr = nbr[(size_t)(b * NP + n0 + row) * KK + k];
        sb[AB + c * 64 + row] = (c < C) ? X[(size_t)(b * NP + jrr) * RSIN + c] : 0.f;
      } else {
#pragma unroll
        for (int i = 0; i < CHUNK / 16; ++i) {
          const int q = wid + i * 4;
          const float4 v = *reinterpret_cast<const float4*>(
              X + (size_t)(b * NP + jr) * RSIN + cc * CHUNK + q * 4);
          sb[AB + (q * 4 + 0) * 64 + lane] = v.x;
          sb[AB + (q * 4 + 1) * 64 + lane] = v.y;
          sb[AB + (q * 4 + 2) * 64 + lane] = v.z;
          sb[AB + (q * 4 + 3) * 64 + lane] = v.w;
        }
      }
      __syncthreads();
#pragma unroll
      for (int c = 0; c < CHUNK; ++c) {
        const float4 a = *reinterpret_cast<const float4*>(sb + AB + c * 64 + tr * 4);
        const float4 bb = *reinterpret_cast<const float4*>(sb + (cc * CHUNK + c) * 64 + tc * 4);
        FMA16(a, bb, acc);
      }
    }
#pragma unroll
    for (int e = 0; e < 4; ++e) {
#pragma unroll
      for (int f = 0; f < 4; ++f) {
        const float h = acc[e][f] + T[e][f];
        mx[e][f] = fmaxf(mx[e][f], h);
        sm[e][f] += h;
        s2[e][f] = fmaf(h, h, s2[e][f]);
      }
    }
  }

#pragma unroll
  for (int e = 0; e < 4; ++e) {
    float4 o4;
    o4.x = mx[e][0]; o4.y = mx[e][1]; o4.z = mx[e][2]; o4.w = mx[e][3];
    *reinterpret_cast<float4*>(outf + (size_t)(b * NP + n0 + tr * 4 + e) * 512 + o0 + tc * 4) = o4;
  }

  __syncthreads();
#pragma unroll
  for (int f = 0; f < 4; ++f) {
    sb[tr * 64 + tc * 4 + f] = sm[0][f] + sm[1][f] + sm[2][f] + sm[3][f];
    sb[1024 + tr * 64 + tc * 4 + f] = s2[0][f] + s2[1][f] + s2[2][f] + s2[3][f];
  }
  __syncthreads();
  if (t < 64) {
    float S = 0.f, Q = 0.f;
#pragma unroll
    for (int r = 0; r < 16; ++r) { S += sb[r * 64 + t]; Q += sb[1024 + r * 64 + t]; }
    atomicAdd(ssum + o0 + t, S);
    atomicAdd(ssq + o0 + t, Q);
  }
}

// ---------------- bn + leaky relu (in place, post-max) ----------------
template<int O>
__global__ __launch_bounds__(256) void bnrelu_kernel(float* __restrict__ feat,
    const float* __restrict__ ssum, const float* __restrict__ ssq,
    const float* __restrict__ g, const float* __restrict__ be) {
  constexpr float INV = 1.0f / 327680.0f;  // B*N*K
  const int t4 = blockIdx.x * 256 + threadIdx.x;
  const int e0 = t4 * 4;
  const int r = e0 / O, c = e0 % O;
  float4 h = *reinterpret_cast<float4*>(feat + (size_t)r * 512 + c);
  float hv[4] = {h.x, h.y, h.z, h.w};
#pragma unroll
  for (int j = 0; j < 4; ++j) {
    const int col = c + j;
    const float m = ssum[col] * INV;
    const float v = ssq[col] * INV - m * m;
    const float sc = g[col] / sqrtf(v + 1e-5f);
    const float val = (hv[j] - m) * sc + be[col];
    hv[j] = (val >= 0.f) ? val : 0.2f * val;
  }
  h.x = hv[0]; h.y = hv[1]; h.z = hv[2]; h.w = hv[3];
  *reinterpret_cast<float4*>(feat + (size_t)r * 512 + c) = h;
}

// ---------------- final conv + global max pool ----------------
__global__ __launch_bounds__(256) void final_kernel(const float* __restrict__ xcat,
    const float* __restrict__ Wf, unsigned int* __restrict__ outenc) {
  __shared__ float sb[9216];  // AT 4096 | WfT 4096 | mred 1024
  const int t = threadIdx.x, lane = t & 63, wid = t >> 6, tr = t & 15, tc = t >> 4;
  const int b = blockIdx.z, n0 = blockIdx.x * 64, o0 = blockIdx.y * 64;
  float acc[4][4] = {};
  for (int cc = 0; cc < 8; ++cc) {
    __syncthreads();
#pragma unroll
    for (int i = 0; i < 4; ++i) {
      const int q = wid + i * 4;
      const float4 v = *reinterpret_cast<const float4*>(
          xcat + (size_t)(b * NP + n0 + lane) * 512 + cc * 64 + q * 4);
      sb[(q * 4 + 0) * 64 + lane] = v.x;
      sb[(q * 4 + 1) * 64 + lane] = v.y;
      sb[(q * 4 + 2) * 64 + lane] = v.z;
      sb[(q * 4 + 3) * 64 + lane] = v.w;
      const float4 w4 = *reinterpret_cast<const float4*>(
          Wf + (size_t)(o0 + lane) * 512 + cc * 64 + q * 4);
      sb[4096 + (q * 4 + 0) * 64 + lane] = w4.x;
      sb[4096 + (q * 4 + 1) * 64 + lane] = w4.y;
      sb[4096 + (q * 4 + 2) * 64 + lane] = w4.z;
      sb[4096 + (q * 4 + 3) * 64 + lane] = w4.w;
    }
    __syncthreads();
#pragma unroll
    for (int c = 0; c < 64; ++c) {
      const float4 a = *reinterpret_cast<const float4*>(sb + c * 64 + tr * 4);
      const float4 bb = *reinterpret_cast<const float4*>(sb + 4096 + c * 64 + tc * 4);
      FMA16(a, bb, acc);
    }
  }
  float m4[4];
#pragma unroll
  for (int f = 0; f < 4; ++f)
    m4[f] = fmaxf(fmaxf(acc[0][f], acc[1][f]), fmaxf(acc[2][f], acc[3][f]));
  __syncthreads();
#pragma unroll
  for (int f = 0; f < 4; ++f) sb[8192 + tr * 64 + tc * 4 + f] = m4[f];
  __syncthreads();
  if (t < 64) {
    float M = -__builtin_inff();
#pragma unroll
    for (int r = 0; r < 16; ++r) M = fmaxf(M, sb[8192 + r * 64 + t]);
    const unsigned ubits = __float_as_uint(M);
    const unsigned key = (ubits & 0x80000000u) ? ~ubits : (ubits | 0x80000000u);
    atomicMax(outenc + b * 1024 + o0 + t, key);
  }
}

__global__ __launch_bounds__(256) void decode_kernel(const unsigned int* __restrict__ enc,
    const float* __restrict__ bf, float* __restrict__ out) {
  const int gid = blockIdx.x * 256 + threadIdx.x;  // 8192
  const unsigned key = enc[gid];
  const unsigned ubits = (key & 0x80000000u) ? (key & 0x7fffffffu) : ~key;
  out[gid] = __uint_as_float(ubits) + bf[gid & 1023];
}

// ---------------- launch ----------------
extern "C" void kernel_launch(void* const* d_in, const int* in_sizes, int n_in,
                              void* d_out, int out_size, void* d_ws, size_t ws_size,
                              hipStream_t stream) {
  (void)in_sizes; (void)n_in; (void)out_size; (void)ws_size;
  const float* x   = (const float*)d_in[0];
  const float* W0  = (const float*)d_in[1];
  const float* b0  = (const float*)d_in[2];
  const float* g0  = (const float*)d_in[3];
  const float* be0 = (const float*)d_in[4];
  const float* W1  = (const float*)d_in[5];
  const float* b1  = (const float*)d_in[6];
  const float* g1  = (const float*)d_in[7];
  const float* be1 = (const float*)d_in[8];
  const float* W2  = (const float*)d_in[9];
  const float* b2  = (const float*)d_in[10];
  const float* g2  = (const float*)d_in[11];
  const float* be2 = (const float*)d_in[12];
  const float* W3  = (const float*)d_in[13];
  const float* b3  = (const float*)d_in[14];
  const float* g3  = (const float*)d_in[15];
  const float* be3 = (const float*)d_in[16];
  const float* Wf  = (const float*)d_in[17];
  const float* bf  = (const float*)d_in[18];

  float* wsf = (float*)d_ws;
  int* idxb = (int*)d_ws;                                  // [8*2048*20] ints
  float* xcat = wsf + 327680;                              // [8][2048][512]
  float* norms = xcat + (size_t)NB * NP * 512;             // [8*2048]
  float* stats = norms + NB * NP;                          // [4][2][256]
  unsigned int* outenc = (unsigned int*)(stats + 2048);    // [8][1024]
  float* x4 = (float*)(outenc + NB * 1024);                // [8*2048][4]
  float* cval = x4 + (size_t)NB * NP * 4;                  // [8*2048][JT*20]
  int* cidx = (int*)(cval + (size_t)NB * NP * JT * KK);    // [8*2048][JT*20]

  hipMemsetAsync(stats, 0, 2048 * sizeof(float), stream);
  hipMemsetAsync(outenc, 0, NB * 1024 * sizeof(unsigned int), stream);

  const dim3 blk(256, 1, 1);
  const dim3 kgrid(32, JT, 8);

  pad_kernel<<<dim3(64), blk, 0, stream>>>(x, x4);

  // Layer 0 (C=3 -> 64, xcat cols [0,64))
  norms_kernel<4, 4><<<dim3(64), blk, 0, stream>>>(x4, norms);
  knn_kernel<4, 4, 1, 4><<<kgrid, blk, 0, stream>>>(x4, norms, cval, cidx);
  knn_merge_kernel<<<dim3(64), blk, 0, stream>>>(cval, cidx, idxb);
  conv_kernel<3, 4, 1, 64, 3><<<dim3(32, 1, 8), blk, 0, stream>>>(
      x, idxb, W0, b0, xcat, stats, stats + 256);
  bnrelu_kernel<64><<<dim3(1024), blk, 0, stream>>>(xcat, stats, stats + 256, g0, be0);

  // Layer 1 (64 -> 64, cols [64,128))
  norms_kernel<64, 512><<<dim3(64), blk, 0, stream>>>(xcat, norms);
  knn_kernel<64, 64, 1, 512><<<kgrid, blk, 0, stream>>>(xcat, norms, cval, cidx);
  knn_merge_kernel<<<dim3(64), blk, 0, stream>>>(cval, cidx, idxb);
  conv_kernel<64, 64, 1, 64, 512><<<dim3(32, 1, 8), blk, 0, stream>>>(
      xcat, idxb, W1, b1, xcat + 64, stats + 512, stats + 768);
  bnrelu_kernel<64><<<dim3(1024), blk, 0, stream>>>(xcat + 64, stats + 512, stats + 768, g1, be1);

  // Layer 2 (64 -> 128, cols [128,256))
  norms_kernel<64, 512><<<dim3(64), blk, 0, stream>>>(xcat + 64, norms);
  knn_kernel<64, 64, 1, 512><<<kgrid, blk, 0, stream>>>(xcat + 64, norms, cval, cidx);
  knn_merge_kernel<<<dim3(64), blk, 0, stream>>>(cval, cidx, idxb);
  conv_kernel<64, 64, 1, 128, 512><<<dim3(32, 2, 8), blk, 0, stream>>>(
      xcat + 64, idxb, W2, b2, xcat + 128, stats + 1024, stats + 1280);
  bnrelu_kernel<128><<<dim3(2048), blk, 0, stream>>>(xcat + 128, stats + 1024, stats + 1280, g2, be2);

  // Layer 3 (128 -> 256, cols [256,512))
  norms_kernel<128, 512><<<dim3(64), blk, 0, stream>>>(xcat + 128, norms);
  knn_kernel<128, 64, 2, 512><<<kgrid, blk, 0, stream>>>(xcat + 128, norms, cval, cidx);
  knn_merge_kernel<<<dim3(64), blk, 0, stream>>>(cval, cidx, idxb);
  conv_kernel<128, 64, 2, 256, 512><<<dim3(32, 4, 8), blk, 0, stream>>>(
      xcat + 128, idxb, W3, b3, xcat + 256, stats + 1536, stats + 1792);
  bnrelu_kernel<256><<<dim3(4096), blk, 0, stream>>>(xcat + 256, stats + 1536, stats + 1792, g3, be3);

  // Final 1x1 conv + global max pool
  final_kernel<<<dim3(32, 16, 8), blk, 0, stream>>>(xcat, Wf, outenc);
  decode_kernel<<<dim3(32), blk, 0, stream>>>(outenc, bf, (float*)d_out);
}